// Round 3
// baseline (188.454 us; speedup 1.0000x reference)
//
#include <hip/hip_runtime.h>

// MaskedContrastiveLoss: loss = 0.5*[mean_i(rowLSE_i - pos_i) + mean_j(colLSE_j - pos_j)]
// logits = (A @ B^T) * (1/0.07), A,B: [256, 65536] fp32 L2-normalized rows.
//
// R3: no-LDS streaming MFMA. The R1/R2 barriered-stage structure caps memory
// duty cycle (vmcnt(0) drain per stage). Here each wave streams its 64x64
// tile's A/B rows straight from global into registers, packs fp32->bf16 with
// v_perm (round-to-nearest via +0x8000), and feeds MFMA -- zero barriers in
// the K-loop, so the compiler software-pipelines with fine-grained vmcnt(N).
// Intra-block split-K (4 waves/tile, LDS-combine once at the end) keeps the
// partial count at C=32 (8 MB). Two dispatches total.

#define D_DIM 65536
#define B_DIM 256
#define C_CHUNKS 32
#define KC (D_DIM / C_CHUNKS)   // 2048 per chunk
#define KCW (KC / 4)            // 512 per wave

constexpr float TEMP = 1.0f / 0.07f;

typedef short short8 __attribute__((ext_vector_type(8)));
typedef float floatx4 __attribute__((ext_vector_type(4)));

__device__ inline unsigned fbits(float f) { return __builtin_bit_cast(unsigned, f); }

// pack two f32 -> two bf16 (round-to-nearest, ties-up) in one v_perm + 2 adds
__device__ inline unsigned pkbf(float lo, float hi) {
  unsigned ul = fbits(lo) + 0x8000u;
  unsigned uh = fbits(hi) + 0x8000u;
  return __builtin_amdgcn_perm(uh, ul, 0x07060302);  // [ul.b2,ul.b3,uh.b2,uh.b3]
}

__device__ inline short8 cvt_frag(float4 a, float4 b) {
  union { unsigned u[4]; short8 s; } r;
  r.u[0] = pkbf(a.x, a.y);
  r.u[1] = pkbf(a.z, a.w);
  r.u[2] = pkbf(b.x, b.y);
  r.u[3] = pkbf(b.z, b.w);
  return r.s;
}

// grid = 16 tiles x C_CHUNKS = 512 blocks, 256 threads (4 waves).
// Block: tile (mt,nt) of chunk; each wave takes KC/4 of the chunk's K range.
__global__ __launch_bounds__(256, 2) void gemm_stream(
    const float* __restrict__ A, const float* __restrict__ Bm,
    float* __restrict__ partials, float* __restrict__ out) {
  if (blockIdx.x == 0 && threadIdx.x == 0) *out = 0.f;  // zero for reduce's atomics

  const int bid = blockIdx.x;
  const int chunk = bid >> 4;
  const int tile = bid & 15;
  const int mt = (tile & 3) * 64;
  const int nt = (tile >> 2) * 64;

  const int t = threadIdx.x;
  const int lane = t & 63;
  const int w = t >> 6;
  const int r16 = lane & 15;   // row within 16 (m or n)
  const int q = lane >> 4;     // quad -> k-offset q*8

  const size_t kb = (size_t)chunk * KC + (size_t)w * KCW;

  const float* pa[4];
  const float* pb[4];
#pragma unroll
  for (int f = 0; f < 4; ++f) {
    pa[f] = A  + (size_t)(mt + f * 16 + r16) * D_DIM + kb + q * 8;
    pb[f] = Bm + (size_t)(nt + f * 16 + r16) * D_DIM + kb + q * 8;
  }

  floatx4 acc[16];
#pragma unroll
  for (int i = 0; i < 16; ++i) acc[i] = (floatx4)0.f;

  float4 xa[8], xb[8], ya[8], yb[8];

#define LOADSET(da, db, off)                                   \
  {                                                            \
    _Pragma("unroll") for (int f = 0; f < 4; ++f) {            \
      da[2 * f]     = *(const float4*)(pa[f] + (off));         \
      da[2 * f + 1] = *(const float4*)(pa[f] + (off) + 4);     \
      db[2 * f]     = *(const float4*)(pb[f] + (off));         \
      db[2 * f + 1] = *(const float4*)(pb[f] + (off) + 4);     \
    }                                                          \
  }

#define COMPUTESET(da, db)                                                    \
  {                                                                           \
    short8 af[4], bf[4];                                                      \
    _Pragma("unroll") for (int f = 0; f < 4; ++f) {                           \
      af[f] = cvt_frag(da[2 * f], da[2 * f + 1]);                             \
      bf[f] = cvt_frag(db[2 * f], db[2 * f + 1]);                             \
    }                                                                         \
    _Pragma("unroll") for (int mb = 0; mb < 4; ++mb)                          \
        _Pragma("unroll") for (int nb = 0; nb < 4; ++nb)                      \
            acc[mb * 4 + nb] = __builtin_amdgcn_mfma_f32_16x16x32_bf16(       \
                af[mb], bf[nb], acc[mb * 4 + nb], 0, 0, 0);                   \
  }

  LOADSET(xa, xb, 0)
#pragma unroll 1
  for (int g = 0; g < KCW / 64; ++g) {  // 8 pairs of K-steps
    LOADSET(ya, yb, g * 64 + 32)
    COMPUTESET(xa, xb)
    if (g + 1 < KCW / 64) LOADSET(xa, xb, g * 64 + 64)
    COMPUTESET(ya, yb)
  }

  // epilogue: combine the 4 waves' K-partials through LDS, write one tile.
  // C/D layout (16x16x32): col = lane&15, row = quad*4 + r.
  __shared__ float red[4][4096];
#pragma unroll
  for (int mb = 0; mb < 4; ++mb)
#pragma unroll
    for (int nb = 0; nb < 4; ++nb)
#pragma unroll
      for (int r = 0; r < 4; ++r)
        red[w][(mb * 16 + q * 4 + r) * 64 + nb * 16 + r16] = acc[mb * 4 + nb][r];
  __syncthreads();

  float* outp = partials + (size_t)chunk * (B_DIM * B_DIM);
#pragma unroll
  for (int jj = 0; jj < 16; ++jj) {
    const int e = jj * 256 + t;  // bank = t%32: conflict-free
    const float v = red[0][e] + red[1][e] + red[2][e] + red[3][e];
    const int row = e >> 6, col = e & 63;
    outp[(size_t)(mt + row) * B_DIM + nt + col] = v;  // lanes -> consecutive cols
  }
#undef LOADSET
#undef COMPUTESET
}

// One fused reduce: block i computes rowLSE_i, colLSE_i, pos_i from partials
// directly (no logits buffer), atomicAdds its term into out.
__global__ __launch_bounds__(256, 4) void reduce_all(
    const float* __restrict__ partials, float* __restrict__ out) {
  const int i = blockIdx.x;
  const int j = threadIdx.x;

  // row i, col j: coalesced across j
  float s = 0.f;
  const float* p = partials + (size_t)i * B_DIM + j;
#pragma unroll
  for (int c = 0; c < C_CHUNKS; ++c) s += p[(size_t)c * (B_DIM * B_DIM)];
  const float lgr = s * TEMP;

  __shared__ float posv;
  if (j == i) posv = lgr;

  // col i, row j: strided, 32 independent loads in flight, L2/LLC-resident
  float s2 = 0.f;
  const float* p2 = partials + (size_t)j * B_DIM + i;
#pragma unroll
  for (int c = 0; c < C_CHUNKS; ++c) s2 += p2[(size_t)c * (B_DIM * B_DIM)];
  const float lgc = s2 * TEMP;

  // |logit| <= TEMP (Cauchy-Schwarz, unit rows): exp is safe without max-shift
  float e1 = expf(lgr);
  float e2 = expf(lgc);
#pragma unroll
  for (int off = 32; off > 0; off >>= 1) {
    e1 += __shfl_down(e1, off);
    e2 += __shfl_down(e2, off);
  }
  __shared__ float w1[4], w2[4];
  if ((j & 63) == 0) { w1[j >> 6] = e1; w2[j >> 6] = e2; }
  __syncthreads();
  if (j == 0) {
    const float rs = w1[0] + w1[1] + w1[2] + w1[3];
    const float cs = w2[0] + w2[1] + w2[2] + w2[3];
    atomicAdd(out, (logf(rs) + logf(cs) - 2.f * posv) * (0.5f / 256.f));
  }
}

extern "C" void kernel_launch(void* const* d_in, const int* in_sizes, int n_in,
                              void* d_out, int out_size, void* d_ws, size_t ws_size,
                              hipStream_t stream) {
  (void)in_sizes; (void)n_in; (void)out_size; (void)ws_size;
  const float* A = (const float*)d_in[0];
  const float* Bm = (const float*)d_in[1];
  float* out = (float*)d_out;
  float* partials = (float*)d_ws;  // C_CHUNKS * 256*256 f32 = 8 MB

  gemm_stream<<<16 * C_CHUNKS, 256, 0, stream>>>(A, Bm, partials, out);
  reduce_all<<<B_DIM, B_DIM, 0, stream>>>(partials, out);
}